// Round 15
// baseline (4219.392 us; speedup 1.0000x reference)
//
#include <hip/hip_runtime.h>

#define B_ 256
#define T_ 512
#define H_ 512
#define P_ 128
#define G4 2048   // 4*H

typedef __attribute__((ext_vector_type(8))) _Float16 h8_t;
typedef __attribute__((ext_vector_type(4))) float floatx4;

__device__ __forceinline__ float sigm(float x){ return 1.0f / (1.0f + __expf(-x)); }
__device__ __forceinline__ float tanh_(float x){ return 2.0f / (1.0f + __expf(-2.0f*x)) - 1.0f; }
__device__ __forceinline__ unsigned short f2h(float f){
  union { _Float16 h; unsigned short u; } c; c.h = (_Float16)f; return c.u;
}
__device__ __forceinline__ float wredsum(float v){
  #pragma unroll
  for (int off = 32; off; off >>= 1) v += __shfl_xor(v, off, 64);
  return v;
}

// Pack enc_Whh (2048x512 fp32 row-major [gate_col][k]) into fp16 MFMA B-frag
// order. tile = (cg*4 + w)*2 + ct; element = tile*8192 + kt*512 + lane*8 + e.
// In-tile col = q*4 + dhc  ->  Whh row = q*512 + cg*32 + w*8 + ct*4 + dhc
// k = kt*32 + (lane>>4)*8 + e
__global__ __launch_bounds__(256) void pack_w(const float* __restrict__ Whh,
                                              unsigned short* __restrict__ Wp){
  int p8   = blockIdx.x * 256 + threadIdx.x;   // 0..131071
  int lane = p8 & 63;
  int kt   = (p8 >> 6) & 15;
  int ct   = (p8 >> 10) & 1;
  int w    = (p8 >> 11) & 3;
  int cg   = (p8 >> 13) & 15;
  int q    = (lane & 15) >> 2, dhc = lane & 3;
  int col  = q*512 + cg*32 + w*8 + ct*4 + dhc;
  int k0   = kt*32 + (lane >> 4)*8;
  const float* s = Whh + (size_t)col * H_ + k0;
  unsigned short v[8];
  #pragma unroll
  for (int e = 0; e < 8; e++) v[e] = f2h(s[e]);
  *(uint4*)(Wp + (size_t)p8 * 8) = *(const uint4*)v;
}

// Persistent encoder: 256 blocks = 16 groups (16 batch rows) x 16 cg (32 hc
// cols). Exchange = R11 summary-flag protocol (PROVEN: drain + summary +
// bulk) with a SPECULATIVE tagged fast path in front:
//   data word(g,row,hp,cg) = {tag=t+1 | 2 x fp16} at
//     D[parity][g*4096 + (row*16+hp)*16 + cg] (consumer's 16 words = 128B).
//   producer: 256 tagged agent RMWs; s_waitcnt vmcnt(0) DRAIN; syncthreads;
//     tid0 summary RMW = t+1.   (identical ordering to R11 -- load-bearing)
//   consumer: up to 3 speculative tagged rounds (steady-state hit: collapses
//     discovery+bulk into ~1 RT); else fall back to sleep-throttled summary
//     poll, then one guaranteed-fresh bulk (drain->summary order).
// Skew <= 1 step (publish requires prior full acquire); both parities
// memset in-graph (replay safety); hang-free (fallback sleeps, RMWs land).
__global__ __launch_bounds__(256) void enc_persist(
    const unsigned short* __restrict__ Wp,
    const float* __restrict__ x,
    const float* __restrict__ Wih,
    const float* __restrict__ bih,
    const float* __restrict__ bhh,
    unsigned long long* __restrict__ D,   // [2 parity][16 g][4096 words]
    unsigned long long* __restrict__ S,   // [2 parity][16 g][16 cg]
    float* __restrict__ hfp,
    float* __restrict__ cfin,
    float* __restrict__ G,
    int zf)
{
  __shared__ float x_lds[16][512];      // 32 KB
  __shared__ uint4 A_lds4[1024];        // 16 KB, XOR-swizzled fp16 A tile
  __shared__ float Sg[4][16][33];       // 8448 B
  __shared__ char pad_[30000];          // total 87.6 KB > 80 KB => 1 block/CU

  char* A_lds = (char*)A_lds4;
  const int bid = blockIdx.x;
  const int tid = threadIdx.x;
  const int lane = tid & 63, wv = tid >> 6;

  if (zf){ pad_[tid] = (char)Wih[tid]; if (!tid) A_lds[0] = pad_[128]; }

  const int g  = bid >> 4;              // batch group (rows g*16..+15)
  const int cg = bid & 15;              // col group   (hc cg*32..+31)

  // ---- W fragments into registers (once): 128 regs/wave
  h8_t wreg[2][16];
  {
    const unsigned short* wb = Wp + (size_t)((cg*4 + wv)*2) * 8192;
    #pragma unroll
    for (int ct = 0; ct < 2; ct++)
      #pragma unroll
      for (int kt = 0; kt < 16; kt++)
        wreg[ct][kt] = *(const h8_t*)(wb + (ct*16 + kt)*512 + lane*8);
  }
  // ---- stage x rows (once)
  #pragma unroll
  for (int i = 0; i < 8; i++){
    int idx = tid + i*256;
    int r = idx >> 7, c4 = (idx & 127)*4;
    *(float4*)&x_lds[r][c4] = *(const float4*)&x[(size_t)(g*16 + r)*T_ + c4];
  }
  // ---- per-thread epilogue: one row (erow), two adjacent hc
  const int erow = tid >> 4;            // 0..15
  const int hp   = tid & 15;            // col-pair slot within block
  const int hc0  = cg*32 + hp*2;
  float wih0[4], wih1[4], bs0[4], bs1[4];
  #pragma unroll
  for (int q = 0; q < 4; q++){
    wih0[q] = Wih[q*512 + hc0];     wih1[q] = Wih[q*512 + hc0 + 1];
    bs0[q]  = bih[q*512 + hc0]     + bhh[q*512 + hc0];
    bs1[q]  = bih[q*512 + hc0 + 1] + bhh[q*512 + hc0 + 1];
  }
  float cr0 = 0.f, cr1 = 0.f;

  // ---- maps. Consumer thread (erow,hp): 16 contiguous words (one per
  // producer cgp); word cgp carries the h pair for hc = cgp*32 + hp*2.
  // LDS byte for that pair: erow*1024 + ((cgp*64 + hp*4) ^ rxor_st).
  const int rxor_st = (erow & 7) << 4;
  int lws[16];
  #pragma unroll
  for (int cgp = 0; cgp < 16; cgp++)
    lws[cgp] = erow*1024 + ((cgp*64 + hp*4) ^ rxor_st);
  const size_t Xrow = (size_t)g*4096 + (size_t)(erow*16 + hp)*16;
  const size_t pidx = Xrow + cg;        // my word (I am producer cg)
  const int arow = lane & 15, ahalf = lane >> 4;
  const int rxor = (arow & 7) << 4;

  unsigned mypay = 0u;                  // my pair of h(-1) = 0

  for (int t = 0; t <= T_; t++){
    const int rpar = (t + 1) & 1;       // parity holding h(t-1)
    const unsigned wtag = (unsigned)t;
    const unsigned long long* Xp = D + (size_t)rpar*65536 + Xrow;
    *(unsigned*)(A_lds + lws[cg]) = mypay;    // self word from registers
    unsigned pend = 0xFFFFu & ~(1u << cg);

    // ---- speculative tagged rounds (fast path: ~1 RT total)
    #pragma unroll 1
    for (int r = 0; r < 3 && pend; r++){
      unsigned long long tmp[16];
      #pragma unroll
      for (int j = 0; j < 16; j++)
        if (pend & (1u << j))
          tmp[j] = __hip_atomic_load(Xp + j, __ATOMIC_RELAXED,
                                     __HIP_MEMORY_SCOPE_AGENT);
      unsigned np = 0u;
      #pragma unroll
      for (int j = 0; j < 16; j++){
        if (pend & (1u << j)){
          if ((unsigned)(tmp[j] >> 32) == wtag)
            *(unsigned*)(A_lds + lws[j]) = (unsigned)tmp[j];
          else
            np |= 1u << j;
        }
      }
      pend = np;
    }
    // ---- fallback: cheap summary discovery + guaranteed-fresh bulk
    if (__syncthreads_or(pend != 0u)){
      if (tid < 16){
        const unsigned long long want = (unsigned long long)t;
        while (__hip_atomic_load(S + rpar*256 + g*16 + tid, __ATOMIC_RELAXED,
                                 __HIP_MEMORY_SCOPE_AGENT) != want)
          __builtin_amdgcn_s_sleep(1);
      }
      __syncthreads();
      if (pend){
        unsigned long long tmp[16];
        #pragma unroll
        for (int j = 0; j < 16; j++)
          if (pend & (1u << j))
            tmp[j] = __hip_atomic_load(Xp + j, __ATOMIC_RELAXED,
                                       __HIP_MEMORY_SCOPE_AGENT);
        #pragma unroll
        for (int j = 0; j < 16; j++)
          if (pend & (1u << j))
            *(unsigned*)(A_lds + lws[j]) = (unsigned)tmp[j];
      }
    }
    __syncthreads();

    floatx4 acc0 = {0,0,0,0}, acc1 = {0,0,0,0};
    h8_t a[16];
    #pragma unroll
    for (int kt = 0; kt < 16; kt++)
      a[kt] = *(const h8_t*)(A_lds + arow*1024 + ((kt*64 + ahalf*16) ^ rxor));
    #pragma unroll
    for (int kt = 0; kt < 16; kt++){
      acc0 = __builtin_amdgcn_mfma_f32_16x16x32_f16(a[kt], wreg[0][kt], acc0, 0,0,0);
      acc1 = __builtin_amdgcn_mfma_f32_16x16x32_f16(a[kt], wreg[1][kt], acc1, 0,0,0);
    }
    // C/D: col = lane&15 (= q*4+dhc), row = (lane>>4)*4 + r
    #pragma unroll
    for (int r = 0; r < 4; r++){
      int srow = ahalf*4 + r;
      int q = (lane & 15) >> 2, dhc = lane & 3;
      Sg[q][srow][wv*8 + dhc]     = acc0[r];
      Sg[q][srow][wv*8 + 4 + dhc] = acc1[r];
    }
    __syncthreads();

    if (t == T_){   // Gconst = h(511)@Whh^T + bsum
      int b = g*16 + erow;
      #pragma unroll
      for (int q = 0; q < 4; q++){
        G[(size_t)b*G4 + q*512 + hc0]     = Sg[q][erow][hp*2]     + bs0[q];
        G[(size_t)b*G4 + q*512 + hc0 + 1] = Sg[q][erow][hp*2 + 1] + bs1[q];
      }
      break;
    }

    const float xb = x_lds[erow][t];
    float pi0 = Sg[0][erow][hp*2] + xb*wih0[0] + bs0[0];
    float pf0 = Sg[1][erow][hp*2] + xb*wih0[1] + bs0[1];
    float pg0 = Sg[2][erow][hp*2] + xb*wih0[2] + bs0[2];
    float po0 = Sg[3][erow][hp*2] + xb*wih0[3] + bs0[3];
    float c20 = sigm(pf0)*cr0 + sigm(pi0)*tanh_(pg0);
    float h0  = sigm(po0)*tanh_(c20);  cr0 = c20;

    float pi1 = Sg[0][erow][hp*2+1] + xb*wih1[0] + bs1[0];
    float pf1 = Sg[1][erow][hp*2+1] + xb*wih1[1] + bs1[1];
    float pg1 = Sg[2][erow][hp*2+1] + xb*wih1[2] + bs1[2];
    float po1 = Sg[3][erow][hp*2+1] + xb*wih1[3] + bs1[3];
    float c21 = sigm(pf1)*cr1 + sigm(pi1)*tanh_(pg1);
    float h1  = sigm(po1)*tanh_(c21);  cr1 = c21;

    // ---- publish h(t): tagged agent RMW per thread
    mypay = (unsigned)f2h(h0) | ((unsigned)f2h(h1) << 16);
    const int wpar = t & 1;
    {
      unsigned long long wo = ((unsigned long long)(t + 1) << 32) | mypay;
      (void)__hip_atomic_exchange(D + (size_t)wpar*65536 + pidx, wo,
                                  __ATOMIC_RELAXED, __HIP_MEMORY_SCOPE_AGENT);
    }
    if (t == T_-1){
      int b = g*16 + erow;
      hfp[(size_t)b*512 + hc0]     = h0;  hfp[(size_t)b*512 + hc0 + 1] = h1;
      cfin[(size_t)b*512 + hc0]    = c20; cfin[(size_t)b*512 + hc0 + 1] = c21;
    }
    // ---- DRAIN (load-bearing, R14 lesson): all data RMWs IF$-acknowledged
    // before the summary publishes; then summary strictly trails data.
    asm volatile("s_waitcnt vmcnt(0)" ::: "memory");
    __syncthreads();
    if (tid == 0)
      (void)__hip_atomic_exchange(S + wpar*256 + g*16 + cg,
                                  (unsigned long long)(t + 1),
                                  __ATOMIC_RELAXED, __HIP_MEMORY_SCOPE_AGENT);
  }
}

// Decoder: scalar recurrence per batch row, one wave per row, zero syncs.
__global__ __launch_bounds__(256) void decoder(
    const float* __restrict__ G, const float* __restrict__ c,
    const float* __restrict__ hfp, const float* __restrict__ Wih,
    const float* __restrict__ dW, const float* __restrict__ db,
    float* __restrict__ out)
{
  const int row  = blockIdx.x * 4 + (threadIdx.x >> 6);
  const int lane = threadIdx.x & 63;
  float Gr[4][8], wr[4][8], cc[8], wd[8];
  float p = 0.f;
  #pragma unroll
  for (int k = 0; k < 8; k++){
    int j = lane + k*64;
    cc[k] = c[(size_t)row*H_ + j];
    wd[k] = dW[j];
    #pragma unroll
    for (int q = 0; q < 4; q++){
      Gr[q][k] = G[(size_t)row*G4 + q*512 + j];
      wr[q][k] = Wih[q*512 + j];
    }
    p += hfp[(size_t)row*H_ + j] * wd[k];
  }
  const float bias = db[0];
  float y = wredsum(p) + bias;
  for (int tt = 0; tt < P_; tt++){
    if (lane == 0) out[(size_t)row*P_ + tt] = y;
    if (tt == P_-1) break;
    float pp = 0.f;
    #pragma unroll
    for (int k = 0; k < 8; k++){
      float i_ = sigm (y*wr[0][k] + Gr[0][k]);
      float f_ = sigm (y*wr[1][k] + Gr[1][k]);
      float g_ = tanh_(y*wr[2][k] + Gr[2][k]);
      float o_ = sigm (y*wr[3][k] + Gr[3][k]);
      float c2 = f_*cc[k] + i_*g_;
      pp += o_*tanh_(c2)*wd[k];
    }
    y = wredsum(pp) + bias;
  }
}

extern "C" void kernel_launch(void* const* d_in, const int* in_sizes, int n_in,
                              void* d_out, int out_size, void* d_ws, size_t ws_size,
                              hipStream_t stream)
{
  const float* x    = (const float*)d_in[0];
  const float* Wih  = (const float*)d_in[1];
  const float* Whh  = (const float*)d_in[2];
  const float* bih  = (const float*)d_in[3];
  const float* bhh  = (const float*)d_in[4];
  // d_in[5..8] = dec_* : provably unused by the reference output
  const float* dW   = (const float*)d_in[9];
  const float* db   = (const float*)d_in[10];
  float* out = (float*)d_out;

  unsigned short* Wp    = (unsigned short*)d_ws;               // 2 MB
  unsigned long long* D = (unsigned long long*)(Wp + 1048576); // 131072 u64 (1 MB)
  unsigned long long* S = D + 131072;                          // 512 u64 (4 KB)
  float* hfp  = (float*)(S + 512);                             // 131072 f32
  float* cfin = hfp + 131072;                                  // 131072 f32
  float* G    = cfin + 131072;                                 // 524288 f32 (2 MB)

  // Clear data + summaries, BOTH parities (tag/summary 0 == wanted at t=0,
  // payload h(-1)=0; in-graph every launch -> replay safe).
  hipMemsetAsync(D, 0, (131072 + 512) * sizeof(unsigned long long), stream);
  pack_w<<<512, 256, 0, stream>>>(Whh, Wp);
  enc_persist<<<256, 256, 0, stream>>>(Wp, x, Wih, bih, bhh, D, S,
                                       hfp, cfin, G, 0);
  decoder<<<64, 256, 0, stream>>>(G, cfin, hfp, Wih, dW, db, out);
}

// Round 16
// 1551.603 us; speedup vs baseline: 2.7194x; 2.7194x over previous
//
#include <hip/hip_runtime.h>

#define B_ 256
#define T_ 512
#define H_ 512
#define P_ 128
#define G4 2048   // 4*H

typedef __attribute__((ext_vector_type(8))) _Float16 h8_t;
typedef __attribute__((ext_vector_type(4))) float floatx4;

__device__ __forceinline__ float sigm(float x){ return 1.0f / (1.0f + __expf(-x)); }
__device__ __forceinline__ float tanh_(float x){ return 2.0f / (1.0f + __expf(-2.0f*x)) - 1.0f; }
__device__ __forceinline__ unsigned short f2h(float f){
  union { _Float16 h; unsigned short u; } c; c.h = (_Float16)f; return c.u;
}
__device__ __forceinline__ float wredsum(float v){
  #pragma unroll
  for (int off = 32; off; off >>= 1) v += __shfl_xor(v, off, 64);
  return v;
}

// Pack enc_Whh (2048x512 fp32 row-major [gate_col][k]) into fp16 MFMA B-frag
// order. tile = (cg*4 + w)*2 + ct; element = tile*8192 + kt*512 + lane*8 + e.
// In-tile col = q*4 + dhc  ->  Whh row = q*512 + cg*32 + w*8 + ct*4 + dhc
// k = kt*32 + (lane>>4)*8 + e
__global__ __launch_bounds__(256) void pack_w(const float* __restrict__ Whh,
                                              unsigned short* __restrict__ Wp){
  int p8   = blockIdx.x * 256 + threadIdx.x;   // 0..131071
  int lane = p8 & 63;
  int kt   = (p8 >> 6) & 15;
  int ct   = (p8 >> 10) & 1;
  int w    = (p8 >> 11) & 3;
  int cg   = (p8 >> 13) & 15;
  int q    = (lane & 15) >> 2, dhc = lane & 3;
  int col  = q*512 + cg*32 + w*8 + ct*4 + dhc;
  int k0   = kt*32 + (lane >> 4)*8;
  const float* s = Whh + (size_t)col * H_ + k0;
  unsigned short v[8];
  #pragma unroll
  for (int e = 0; e < 8; e++) v[e] = f2h(s[e]);
  *(uint4*)(Wp + (size_t)p8 * 8) = *(const uint4*)v;
}

// Persistent encoder: 256 blocks = 16 groups (16 batch rows) x 16 cg (32 hc
// cols). Exchange protocol (summary-flag, single agent rail — PROVEN best
// of 6 protocol shapes tested, R5..R15):
//   producer: 128 UNTAGGED fp16x4 data words via agent RMW; per-wave
//     s_waitcnt vmcnt(0) DRAIN (load-bearing, R14); __syncthreads; tid0
//     publishes summary = t+1 (agent RMW, strictly trails data).
//   consumer: threads 0..15 poll the 16 producer summaries (2 cache lines
//     per block per round — ~1000x less poll traffic than tagged-direct);
//     then whole block bulk-loads the group's 16KB h-slab once (coalesced
//     agent loads) and stages to XOR-swizzled LDS.
// Parity double-buffer; lockstep summary gate makes overwrite races
// impossible; both parities memset each launch (replay safety).
__global__ __launch_bounds__(256) void enc_persist(
    const unsigned short* __restrict__ Wp,
    const float* __restrict__ x,
    const float* __restrict__ Wih,
    const float* __restrict__ bih,
    const float* __restrict__ bhh,
    unsigned long long* __restrict__ D,   // data  [2][16 g][16 row][128 c4]
    unsigned long long* __restrict__ S,   // summ  [2][16 g][16 cg]
    float* __restrict__ hfp,
    float* __restrict__ cfin,
    float* __restrict__ G,
    int zf)
{
  __shared__ float x_lds[16][512];      // 32 KB
  __shared__ uint4 A_lds4[1024];        // 16 KB, XOR-swizzled fp16 A tile
  __shared__ float Sg[4][16][33];       // 8448 B
  __shared__ char pad_[30000];          // total 87.6 KB > 80 KB => 1 block/CU

  char* A_lds = (char*)A_lds4;
  const int bid = blockIdx.x;
  const int tid = threadIdx.x;
  const int lane = tid & 63, wv = tid >> 6;

  if (zf){ pad_[tid] = (char)Wih[tid]; if (!tid) A_lds[0] = pad_[128]; }

  const int g  = bid >> 4;              // batch group (rows g*16..+15)
  const int cg = bid & 15;              // col group   (hc cg*32..+31)

  // ---- W fragments into registers (once): 128 regs/wave
  h8_t wreg[2][16];
  {
    const unsigned short* wb = Wp + (size_t)((cg*4 + wv)*2) * 8192;
    #pragma unroll
    for (int ct = 0; ct < 2; ct++)
      #pragma unroll
      for (int kt = 0; kt < 16; kt++)
        wreg[ct][kt] = *(const h8_t*)(wb + (ct*16 + kt)*512 + lane*8);
  }
  // ---- stage x rows (once)
  #pragma unroll
  for (int i = 0; i < 8; i++){
    int idx = tid + i*256;
    int r = idx >> 7, c4 = (idx & 127)*4;
    *(float4*)&x_lds[r][c4] = *(const float4*)&x[(size_t)(g*16 + r)*T_ + c4];
  }
  // ---- per-thread epilogue: one row (erow), two adjacent hc
  const int erow = tid >> 4;            // 0..15
  const int hp   = tid & 15;
  const int hc0  = cg*32 + hp*2;
  float wih0[4], wih1[4], bs0[4], bs1[4];
  #pragma unroll
  for (int q = 0; q < 4; q++){
    wih0[q] = Wih[q*512 + hc0];     wih1[q] = Wih[q*512 + hc0 + 1];
    bs0[q]  = bih[q*512 + hc0]     + bhh[q*512 + hc0];
    bs1[q]  = bih[q*512 + hc0 + 1] + bhh[q*512 + hc0 + 1];
  }
  float cr0 = 0.f, cr1 = 0.f;

  // ---- maps ----
  // bulk loader: thread (r=erow, hp) loads words c4 = hp + wi*16, wi=0..7
  //   LDS byte = r*1024 + ((hp*8 + wi*128) ^ rxor_st)  [8B-granule safe]
  const int rxor_st = (erow & 7) << 4;
  const size_t Dg = (size_t)g * 2048;               // group slab base (words)
  // producer: even-hp thread publishes word c4 = cg*8 + hp/2 for its row
  const size_t pidx = Dg + (size_t)erow*128 + cg*8 + (hp >> 1);
  const int arow = lane & 15, ahalf = lane >> 4;
  const int rxor = (arow & 7) << 4;

  for (int t = 0; t <= T_; t++){
    const int rpar = (t + 1) & 1;       // parity holding h(t-1)
    // ---- discovery: 16 summaries must equal t (h(t-1) published).
    // No sleep: dependent-load latency self-throttles; 16 thr x 2 lines
    // per block per round is negligible fabric traffic.
    if (tid < 16){
      const unsigned long long want = (unsigned long long)t;
      while (__hip_atomic_load(S + rpar*256 + g*16 + tid, __ATOMIC_RELAXED,
                               __HIP_MEMORY_SCOPE_AGENT) != want)
        ;
    }
    __syncthreads();
    // ---- bulk load group's 16KB slab (untagged fp16x4), stage to LDS
    {
      const unsigned long long* Db = D + (size_t)rpar*32768 + Dg
                                       + (size_t)erow*128 + hp;
      unsigned long long wbuf[8];
      #pragma unroll
      for (int wi = 0; wi < 8; wi++)
        wbuf[wi] = __hip_atomic_load(Db + wi*16, __ATOMIC_RELAXED,
                                     __HIP_MEMORY_SCOPE_AGENT);
      #pragma unroll
      for (int wi = 0; wi < 8; wi++)
        *(unsigned long long*)(A_lds + erow*1024 + ((hp*8 + wi*128) ^ rxor_st))
            = wbuf[wi];
    }
    __syncthreads();

    floatx4 acc0 = {0,0,0,0}, acc1 = {0,0,0,0};
    h8_t a[16];
    #pragma unroll
    for (int kt = 0; kt < 16; kt++)
      a[kt] = *(const h8_t*)(A_lds + arow*1024 + ((kt*64 + ahalf*16) ^ rxor));
    #pragma unroll
    for (int kt = 0; kt < 16; kt++){
      acc0 = __builtin_amdgcn_mfma_f32_16x16x32_f16(a[kt], wreg[0][kt], acc0, 0,0,0);
      acc1 = __builtin_amdgcn_mfma_f32_16x16x32_f16(a[kt], wreg[1][kt], acc1, 0,0,0);
    }
    // C/D: col = lane&15 (= q*4+dhc), row = (lane>>4)*4 + r
    #pragma unroll
    for (int r = 0; r < 4; r++){
      int srow = ahalf*4 + r;
      int q = (lane & 15) >> 2, dhc = lane & 3;
      Sg[q][srow][wv*8 + dhc]     = acc0[r];
      Sg[q][srow][wv*8 + 4 + dhc] = acc1[r];
    }
    __syncthreads();

    if (t == T_){   // Gconst = h(511)@Whh^T + bsum
      int b = g*16 + erow;
      #pragma unroll
      for (int q = 0; q < 4; q++){
        G[(size_t)b*G4 + q*512 + hc0]     = Sg[q][erow][hp*2]     + bs0[q];
        G[(size_t)b*G4 + q*512 + hc0 + 1] = Sg[q][erow][hp*2 + 1] + bs1[q];
      }
      break;
    }

    const float xb = x_lds[erow][t];
    float pi0 = Sg[0][erow][hp*2] + xb*wih0[0] + bs0[0];
    float pf0 = Sg[1][erow][hp*2] + xb*wih0[1] + bs0[1];
    float pg0 = Sg[2][erow][hp*2] + xb*wih0[2] + bs0[2];
    float po0 = Sg[3][erow][hp*2] + xb*wih0[3] + bs0[3];
    float c20 = sigm(pf0)*cr0 + sigm(pi0)*tanh_(pg0);
    float h0  = sigm(po0)*tanh_(c20);  cr0 = c20;

    float pi1 = Sg[0][erow][hp*2+1] + xb*wih1[0] + bs1[0];
    float pf1 = Sg[1][erow][hp*2+1] + xb*wih1[1] + bs1[1];
    float pg1 = Sg[2][erow][hp*2+1] + xb*wih1[2] + bs1[2];
    float po1 = Sg[3][erow][hp*2+1] + xb*wih1[3] + bs1[3];
    float c21 = sigm(pf1)*cr1 + sigm(pi1)*tanh_(pg1);
    float h1  = sigm(po1)*tanh_(c21);  cr1 = c21;

    // ---- publish data (untagged fp16x4): even-hp threads, 128/block
    unsigned pay = (unsigned)f2h(h0) | ((unsigned)f2h(h1) << 16);
    unsigned payN = __shfl_xor(pay, 1);           // neighbor's 2 cols
    const int wpar = t & 1;
    if (!(hp & 1)){
      unsigned long long wo = (unsigned long long)pay
                            | ((unsigned long long)payN << 32);
      (void)__hip_atomic_exchange(D + (size_t)wpar*32768 + pidx, wo,
                                  __ATOMIC_RELAXED, __HIP_MEMORY_SCOPE_AGENT);
    }
    // drain this wave's RMWs to the coherence point, then block-sync,
    // then one summary RMW (guaranteed to trail all data words)
    asm volatile("s_waitcnt vmcnt(0)" ::: "memory");
    __syncthreads();
    if (tid == 0)
      (void)__hip_atomic_exchange(S + wpar*256 + g*16 + cg,
                                  (unsigned long long)(t + 1),
                                  __ATOMIC_RELAXED, __HIP_MEMORY_SCOPE_AGENT);

    if (t == T_-1){
      int b = g*16 + erow;
      hfp[(size_t)b*512 + hc0]     = h0;  hfp[(size_t)b*512 + hc0 + 1] = h1;
      cfin[(size_t)b*512 + hc0]    = c20; cfin[(size_t)b*512 + hc0 + 1] = c21;
    }
  }
}

// Decoder: scalar recurrence per batch row, one wave per row, zero syncs.
__global__ __launch_bounds__(256) void decoder(
    const float* __restrict__ G, const float* __restrict__ c,
    const float* __restrict__ hfp, const float* __restrict__ Wih,
    const float* __restrict__ dW, const float* __restrict__ db,
    float* __restrict__ out)
{
  const int row  = blockIdx.x * 4 + (threadIdx.x >> 6);
  const int lane = threadIdx.x & 63;
  float Gr[4][8], wr[4][8], cc[8], wd[8];
  float p = 0.f;
  #pragma unroll
  for (int k = 0; k < 8; k++){
    int j = lane + k*64;
    cc[k] = c[(size_t)row*H_ + j];
    wd[k] = dW[j];
    #pragma unroll
    for (int q = 0; q < 4; q++){
      Gr[q][k] = G[(size_t)row*G4 + q*512 + j];
      wr[q][k] = Wih[q*512 + j];
    }
    p += hfp[(size_t)row*H_ + j] * wd[k];
  }
  const float bias = db[0];
  float y = wredsum(p) + bias;
  for (int tt = 0; tt < P_; tt++){
    if (lane == 0) out[(size_t)row*P_ + tt] = y;
    if (tt == P_-1) break;
    float pp = 0.f;
    #pragma unroll
    for (int k = 0; k < 8; k++){
      float i_ = sigm (y*wr[0][k] + Gr[0][k]);
      float f_ = sigm (y*wr[1][k] + Gr[1][k]);
      float g_ = tanh_(y*wr[2][k] + Gr[2][k]);
      float o_ = sigm (y*wr[3][k] + Gr[3][k]);
      float c2 = f_*cc[k] + i_*g_;
      pp += o_*tanh_(c2)*wd[k];
    }
    y = wredsum(pp) + bias;
  }
}

extern "C" void kernel_launch(void* const* d_in, const int* in_sizes, int n_in,
                              void* d_out, int out_size, void* d_ws, size_t ws_size,
                              hipStream_t stream)
{
  const float* x    = (const float*)d_in[0];
  const float* Wih  = (const float*)d_in[1];
  const float* Whh  = (const float*)d_in[2];
  const float* bih  = (const float*)d_in[3];
  const float* bhh  = (const float*)d_in[4];
  // d_in[5..8] = dec_* : provably unused by the reference output
  const float* dW   = (const float*)d_in[9];
  const float* db   = (const float*)d_in[10];
  float* out = (float*)d_out;

  unsigned short* Wp    = (unsigned short*)d_ws;               // 2 MB
  unsigned long long* D = (unsigned long long*)(Wp + 1048576); // 65536 u64 (512 KB)
  unsigned long long* S = D + 65536;                           // 512 u64 (4 KB)
  float* hfp  = (float*)(S + 512);                             // 131072 f32
  float* cfin = hfp + 131072;                                  // 131072 f32
  float* G    = cfin + 131072;                                 // 524288 f32 (2 MB)

  // Clear data + summaries, BOTH parities (h(-1)=0; summary 0 == wanted
  // tag at t=0; replay safety — runs inside the graph every launch).
  hipMemsetAsync(D, 0, (65536 + 512) * sizeof(unsigned long long), stream);
  pack_w<<<512, 256, 0, stream>>>(Whh, Wp);
  enc_persist<<<256, 256, 0, stream>>>(Wp, x, Wih, bih, bhh, D, S,
                                       hfp, cfin, G, 0);
  decoder<<<64, 256, 0, stream>>>(G, cfin, hfp, Wih, dW, db, out);
}